// Round 1
// baseline (775.564 us; speedup 1.0000x reference)
//
#include <hip/hip_runtime.h>

// Problem constants (fixed shapes from the reference).
#define T_TYPES 27
#define N_NODES 16384
#define B_BATCH 256
#define IN_DIM 300
#define HID 128
#define OUTD 64

#define RPB 32          // batch rows per MLP block
#define VEC 75          // 300 floats = 75 float4 per row

// ---------------------------------------------------------------------------
// Kernel 1: ragged segment mean pooling.
// segment_ids are sorted per type, so segment (t, b) is a contiguous node
// range [lb(b), lb(b+1)). One block per (t, b): binary search boundaries,
// stream the rows with float4 loads, reduce over the 4-way node split in LDS.
// grid (B, T), block (80, 4): x = float4 column (75 active), y = node phase.
// ---------------------------------------------------------------------------
__global__ __launch_bounds__(320) void pool_kernel(
    const float* __restrict__ feat,   // [T, N, 300]
    const int*   __restrict__ seg,    // [T, N] sorted in [0, B)
    float*       __restrict__ pooled) // [T, B, 300]
{
    const int b = blockIdx.x;
    const int t = blockIdx.y;

    __shared__ int sBound[2];
    __shared__ float4 sAcc[4][80];

    if (threadIdx.x == 0 && threadIdx.y == 0) {
        const int* s = seg + (size_t)t * N_NODES;
        // lower_bound(b)
        int lo = 0, hi = N_NODES;
        while (lo < hi) { int m = (lo + hi) >> 1; if (s[m] < b) lo = m + 1; else hi = m; }
        sBound[0] = lo;
        // lower_bound(b+1), can start from lo
        int lo2 = lo; hi = N_NODES;
        while (lo2 < hi) { int m = (lo2 + hi) >> 1; if (s[m] < b + 1) lo2 = m + 1; else hi = m; }
        sBound[1] = lo2;
    }
    __syncthreads();

    const int start = sBound[0];
    const int end   = sBound[1];
    const int x = threadIdx.x;
    const int y = threadIdx.y;

    float4 acc = make_float4(0.f, 0.f, 0.f, 0.f);
    if (x < VEC) {
        const float4* __restrict__ fv = (const float4*)feat;
        const size_t rowBase = (size_t)t * N_NODES;
        int n = start + y;
        // 4-deep unroll: 4 outstanding float4 loads per wave for latency hiding
        for (; n + 12 < end; n += 16) {
            float4 v0 = fv[(rowBase + n     ) * VEC + x];
            float4 v1 = fv[(rowBase + n + 4 ) * VEC + x];
            float4 v2 = fv[(rowBase + n + 8 ) * VEC + x];
            float4 v3 = fv[(rowBase + n + 12) * VEC + x];
            acc.x += v0.x + v1.x + v2.x + v3.x;
            acc.y += v0.y + v1.y + v2.y + v3.y;
            acc.z += v0.z + v1.z + v2.z + v3.z;
            acc.w += v0.w + v1.w + v2.w + v3.w;
        }
        for (; n < end; n += 4) {
            float4 v = fv[(rowBase + n) * VEC + x];
            acc.x += v.x; acc.y += v.y; acc.z += v.z; acc.w += v.w;
        }
    }
    sAcc[y][x] = acc;
    __syncthreads();

    if (y == 0 && x < VEC) {
        float4 a0 = sAcc[0][x], a1 = sAcc[1][x], a2 = sAcc[2][x], a3 = sAcc[3][x];
        const int cnt = end - start;
        const float scale = (cnt > 0) ? (1.0f / (float)cnt) : 0.0f;
        float4 r;
        r.x = (a0.x + a1.x + a2.x + a3.x) * scale;
        r.y = (a0.y + a1.y + a2.y + a3.y) * scale;
        r.z = (a0.z + a1.z + a2.z + a3.z) * scale;
        r.w = (a0.w + a1.w + a2.w + a3.w) * scale;
        ((float4*)pooled)[((size_t)t * B_BATCH + b) * VEC + x] = r;
    }
}

// ---------------------------------------------------------------------------
// Kernel 2: per-type 2-layer MLP on pooled rows.
// grid (B/RPB, T), block 256. Stage 32 pooled rows in LDS (stride 301,
// odd -> conflict-free across 32 r-lanes). Layer 1: thread = (r, hq) computes
// 16 h outputs; W1 reads are lane-broadcast across the 32 r-lanes (L1
// broadcast). h staged in LDS (stride 129). Layer 2 analogous with 8 outputs.
// ---------------------------------------------------------------------------
__global__ __launch_bounds__(256) void mlp_kernel(
    const float* __restrict__ pooled, // [T, B, 300]
    const float* __restrict__ W1,     // [T, 300, 128]
    const float* __restrict__ b1,     // [T, 128]
    const float* __restrict__ W2,     // [T, 128, 64]
    const float* __restrict__ b2,     // [T, 64]
    float*       __restrict__ out)    // [B, T, 64]
{
    const int t  = blockIdx.y;
    const int b0 = blockIdx.x * RPB;
    const int tid = threadIdx.x;

    __shared__ float sP[RPB][IN_DIM + 1]; // stride 301 (301%32=13, odd)
    __shared__ float sH[RPB][HID + 1];    // stride 129 (129%32=1)

    // stage pooled rows (coalesced global read, scalar LDS writes)
    {
        const float* __restrict__ psrc =
            pooled + ((size_t)t * B_BATCH + b0) * IN_DIM;
        for (int idx = tid; idx < RPB * IN_DIM; idx += 256) {
            int r = idx / IN_DIM;
            int i = idx - r * IN_DIM;
            sP[r][i] = psrc[idx];
        }
    }
    __syncthreads();

    // ---- layer 1: h = relu(p @ W1 + b1) ----
    {
        const int r  = tid & 31;
        const int hq = tid >> 5;          // 8 groups x 16 h
        float acc[16];
        {
            const float* __restrict__ bb = b1 + t * HID + hq * 16;
            #pragma unroll
            for (int j = 0; j < 16; ++j) acc[j] = bb[j];
        }
        const float* __restrict__ w1p =
            W1 + (size_t)t * IN_DIM * HID + hq * 16;
        #pragma unroll 2
        for (int i = 0; i < IN_DIM; ++i) {
            const float p = sP[r][i];
            const float4* __restrict__ w = (const float4*)(w1p + (size_t)i * HID);
            float4 wv[4];
            wv[0] = w[0]; wv[1] = w[1]; wv[2] = w[2]; wv[3] = w[3];
            #pragma unroll
            for (int q = 0; q < 4; ++q) {
                acc[q * 4 + 0] += p * wv[q].x;
                acc[q * 4 + 1] += p * wv[q].y;
                acc[q * 4 + 2] += p * wv[q].z;
                acc[q * 4 + 3] += p * wv[q].w;
            }
        }
        #pragma unroll
        for (int j = 0; j < 16; ++j)
            sH[r][hq * 16 + j] = fmaxf(acc[j], 0.0f);
    }
    __syncthreads();

    // ---- layer 2: out = h @ W2 + b2 ----
    {
        const int r  = tid & 31;
        const int oq = tid >> 5;          // 8 groups x 8 outputs
        float acc[8];
        {
            const float* __restrict__ bb = b2 + t * OUTD + oq * 8;
            #pragma unroll
            for (int j = 0; j < 8; ++j) acc[j] = bb[j];
        }
        const float* __restrict__ w2p =
            W2 + (size_t)t * HID * OUTD + oq * 8;
        #pragma unroll 2
        for (int k = 0; k < HID; ++k) {
            const float h = sH[r][k];
            const float4* __restrict__ w = (const float4*)(w2p + (size_t)k * OUTD);
            float4 w0 = w[0], w1v = w[1];
            acc[0] += h * w0.x;  acc[1] += h * w0.y;
            acc[2] += h * w0.z;  acc[3] += h * w0.w;
            acc[4] += h * w1v.x; acc[5] += h * w1v.y;
            acc[6] += h * w1v.z; acc[7] += h * w1v.w;
        }
        // out[b0+r][t][oq*8 .. +7]
        float* __restrict__ op =
            out + ((size_t)(b0 + r) * T_TYPES + t) * OUTD + oq * 8;
        #pragma unroll
        for (int j = 0; j < 8; ++j) op[j] = acc[j];
    }
}

extern "C" void kernel_launch(void* const* d_in, const int* in_sizes, int n_in,
                              void* d_out, int out_size, void* d_ws, size_t ws_size,
                              hipStream_t stream) {
    const float* feat = (const float*)d_in[0];
    const int*   seg  = (const int*)  d_in[1];
    const float* W1   = (const float*)d_in[2];
    const float* b1   = (const float*)d_in[3];
    const float* W2   = (const float*)d_in[4];
    const float* b2   = (const float*)d_in[5];
    float* out = (float*)d_out;

    float* pooled = (float*)d_ws;   // 27*256*300 f32 = 8.3 MB scratch

    dim3 g1(B_BATCH, T_TYPES), blk1(80, 4);
    hipLaunchKernelGGL(pool_kernel, g1, blk1, 0, stream, feat, seg, pooled);

    dim3 g2(B_BATCH / RPB, T_TYPES), blk2(256);
    hipLaunchKernelGGL(mlp_kernel, g2, blk2, 0, stream,
                       pooled, W1, b1, W2, b2, out);
}